// Round 6
// baseline (83.020 us; speedup 1.0000x reference)
//
#include <hip/hip_runtime.h>
#include <hip/hip_bf16.h>

// PerPixelConv: out[b,c,h,w] = sum_{dy,dx} input_zp[b,c,h+dy-1,w+dx-1] * kernel[b,dy*3+dx,h,w]
// input [8,3,720,1280] f32, kernel [8,9,720,1280] f32, out [8,3,720,1280] f32.
// Memory-bound (442 MB compulsory). Ladder: R1 naive 93.4us -> R3 +XCD swizzle
// +NT 83.8us -> R4 8px/thread REGRESSION 103.7us (strided lanes halve coalesce
// density) -> R5 shuffle-halo 78.5us (5.63 TB/s = 89% of 6.29 TB/s copy ceiling).
// R6: occupancy push. dy-outer/c-inner loop so only 3 kernel taps (12 VGPR) are
// live at a time instead of 9 (36 VGPR); acc[3] persists. launch_bounds(256,8)
// caps VGPR at 64 -> 8 waves/SIMD (32 waves/CU, max) for more loads in flight.
// Edge loads exec-predicated to lanes 0/63.

#ifndef PPC_CONSTS
#define PPC_CONSTS
constexpr int PB = 8, PC = 3, PH = 720, PW = 1280;
constexpr int PHW = PH * PW;
constexpr int PWG = PW / 4;              // float4 groups per row = 320
constexpr int PTOTAL = PB * PH * PWG;    // 1,843,200 threads
constexpr int PBLK = 256;
constexpr int PNBLK = PTOTAL / PBLK;     // 7200 blocks (exact)
constexpr int PNXCD = 8;
constexpr int PCHUNK = PNBLK / PNXCD;    // 900 (bijective: 7200 % 8 == 0)
typedef float f32x4 __attribute__((ext_vector_type(4)));
#endif

__global__ __launch_bounds__(PBLK, 8) void PerPixelConv_kernel(
    const float* __restrict__ input,
    const float* __restrict__ kernel,
    float* __restrict__ out)
{
    // XCD-aware chunked swizzle: XCD x handles one contiguous batch image.
    int lb  = (blockIdx.x % PNXCD) * PCHUNK + blockIdx.x / PNXCD;
    int idx = lb * PBLK + threadIdx.x;
    int lane = threadIdx.x & 63;

    int wg = idx % PWG;
    int h  = (idx / PWG) % PH;           // wave-uniform (64 | 320)
    int b  = idx / (PWG * PH);           // wave-uniform
    int w0 = wg * 4;

    const float* kbase = kernel + (size_t)b * 9 * PHW + (size_t)h * PW + w0;
    const float* ibase = input  + (size_t)b * PC * PHW + w0;

    // Halo handling: lane 0 needs r[-1], lane 63 needs r[4]; image borders -> 0.
    const bool leftEdge  = (w0 == 0);        // only possible for lane 0
    const bool rightEdge = (w0 + 4 == PW);   // only possible for lane 63
    const bool edgeLane  = (lane == 0) || (lane == 63);
    const int  eoff = (lane == 0) ? (leftEdge ? 0 : -1)
                                  : (rightEdge ? 3 : 4);

    f32x4 acc[PC];
    #pragma unroll
    for (int c = 0; c < PC; ++c) acc[c] = (f32x4)0.f;

    #pragma unroll
    for (int dy = 0; dy < 3; ++dy) {
        int row = h + dy - 1;
        if (row < 0 || row >= PH) continue;   // wave-uniform zero-pad skip

        // Kernel taps for this dy only (12 VGPR transient, single-use -> NT).
        f32x4 kd[3];
        #pragma unroll
        for (int dx = 0; dx < 3; ++dx)
            kd[dx] = __builtin_nontemporal_load(
                         reinterpret_cast<const f32x4*>(kbase + (size_t)(dy * 3 + dx) * PHW));

        #pragma unroll
        for (int c = 0; c < PC; ++c) {
            const float* r = ibase + (size_t)c * PHW + (size_t)row * PW;
            f32x4 mid = *reinterpret_cast<const f32x4*>(r);
            float edge = 0.f;
            if (edgeLane) edge = r[eoff];     // exec-masked: 2 lanes fetch

            float x0 = __shfl_up(mid.w, 1);   // lane i <- lane i-1's w0+3
            if (lane == 0)  x0 = leftEdge  ? 0.f : edge;
            float x5 = __shfl_down(mid.x, 1); // lane i <- lane i+1's w0
            if (lane == 63) x5 = rightEdge ? 0.f : edge;

            acc[c].x += x0    * kd[0].x + mid.x * kd[1].x + mid.y * kd[2].x;
            acc[c].y += mid.x * kd[0].y + mid.y * kd[1].y + mid.z * kd[2].y;
            acc[c].z += mid.y * kd[0].z + mid.z * kd[1].z + mid.w * kd[2].z;
            acc[c].w += mid.z * kd[0].w + mid.w * kd[1].w + x5    * kd[2].w;
        }
    }

    float* obase = out + (size_t)b * PC * PHW + (size_t)h * PW + w0;
    #pragma unroll
    for (int c = 0; c < PC; ++c)
        __builtin_nontemporal_store(
            acc[c], reinterpret_cast<f32x4*>(obase + (size_t)c * PHW));
}

extern "C" void kernel_launch(void* const* d_in, const int* in_sizes, int n_in,
                              void* d_out, int out_size, void* d_ws, size_t ws_size,
                              hipStream_t stream) {
    const float* input  = (const float*)d_in[0];
    const float* kernel = (const float*)d_in[1];
    float* out = (float*)d_out;

    PerPixelConv_kernel<<<PNBLK, PBLK, 0, stream>>>(input, kernel, out);
}

// Round 7
// 76.182 us; speedup vs baseline: 1.0897x; 1.0897x over previous
//
#include <hip/hip_runtime.h>
#include <hip/hip_bf16.h>

// PerPixelConv: out[b,c,h,w] = sum_{dy,dx} input_zp[b,c,h+dy-1,w+dx-1] * kernel[b,dy*3+dx,h,w]
// input [8,3,720,1280] f32, kernel [8,9,720,1280] f32, out [8,3,720,1280] f32.
// Memory-bound (442 MB compulsory -> 70us floor at 6.3 TB/s).
// Ladder: R1 naive 93.4 -> R3 +XCD-chunk swizzle +NT 83.8 -> R4 8px/thread
// REGRESSION 103.7 (strided lanes halve coalesce density) -> R5 shuffle-halo
// 78.5 (5.63 TB/s) -> R6 dy-outer + launch_bounds(,8) REGRESSION 83.0
// (serialized the 9-load kernel batch -> lost per-wave MLP; occupancy didn't
// compensate). Lesson: issue independent loads in one batch.
// R7: exact R5 structure (9 kv loads up front, c-outer/dy-inner, R5 FMA order
// for absmax=0) + edge scalar loads exec-predicated to lanes 0/63 only.

#ifndef PPC_CONSTS
#define PPC_CONSTS
constexpr int PB = 8, PC = 3, PH = 720, PW = 1280;
constexpr int PHW = PH * PW;
constexpr int PWG = PW / 4;              // float4 groups per row = 320
constexpr int PTOTAL = PB * PH * PWG;    // 1,843,200 threads
constexpr int PBLK = 256;
constexpr int PNBLK = PTOTAL / PBLK;     // 7200 blocks (exact)
constexpr int PNXCD = 8;
constexpr int PCHUNK = PNBLK / PNXCD;    // 900 (bijective: 7200 % 8 == 0)
typedef float f32x4 __attribute__((ext_vector_type(4)));
#endif

__global__ __launch_bounds__(PBLK) void PerPixelConv_kernel(
    const float* __restrict__ input,
    const float* __restrict__ kernel,
    float* __restrict__ out)
{
    // XCD-aware chunked swizzle: XCD x handles one contiguous batch image.
    int lb  = (blockIdx.x % PNXCD) * PCHUNK + blockIdx.x / PNXCD;
    int idx = lb * PBLK + threadIdx.x;
    int lane = threadIdx.x & 63;

    int wg = idx % PWG;
    int h  = (idx / PWG) % PH;           // wave-uniform (64 | 320)
    int b  = idx / (PWG * PH);           // wave-uniform
    int w0 = wg * 4;

    // 9 per-pixel kernel taps, issued as one independent batch (MLP) -> NT.
    const float* kbase = kernel + (size_t)b * 9 * PHW + (size_t)h * PW + w0;
    f32x4 kv[9];
    #pragma unroll
    for (int k = 0; k < 9; ++k)
        kv[k] = __builtin_nontemporal_load(
                    reinterpret_cast<const f32x4*>(kbase + (size_t)k * PHW));

    const float* ibase = input + (size_t)b * PC * PHW;
    float*       obase = out   + (size_t)b * PC * PHW;

    // Halo: lane 0 needs r[-1], lane 63 needs r[4]; image borders -> 0.
    const bool leftEdge  = (w0 == 0);        // only possible for lane 0
    const bool rightEdge = (w0 + 4 == PW);   // only possible for lane 63
    const bool edgeLane  = (lane == 0) || (lane == 63);
    const int  eoff = (lane == 0) ? (leftEdge ? 0 : -1)
                                  : (rightEdge ? 3 : 4);

    #pragma unroll
    for (int c = 0; c < PC; ++c) {
        float acc0 = 0.f, acc1 = 0.f, acc2 = 0.f, acc3 = 0.f;
        #pragma unroll
        for (int dy = 0; dy < 3; ++dy) {
            int row = h + dy - 1;
            if (row < 0 || row >= PH) continue;   // wave-uniform zero-pad skip
            const float* r = ibase + (size_t)c * PHW + (size_t)row * PW + w0;
            f32x4 mid = *reinterpret_cast<const f32x4*>(r);
            float edge = 0.f;
            if (edgeLane) edge = r[eoff];         // exec-masked: 2 lanes fetch

            float x0 = __shfl_up(mid.w, 1);       // lane i <- lane i-1's w0+3
            if (lane == 0)  x0 = leftEdge  ? 0.f : edge;
            float x5 = __shfl_down(mid.x, 1);     // lane i <- lane i+1's w0
            if (lane == 63) x5 = rightEdge ? 0.f : edge;

            float x1 = mid.x, x2 = mid.y, x3 = mid.z, x4 = mid.w;

            f32x4 k0 = kv[dy * 3 + 0];
            f32x4 k1 = kv[dy * 3 + 1];
            f32x4 k2 = kv[dy * 3 + 2];
            acc0 += x0 * k0.x;  acc1 += x1 * k0.y;  acc2 += x2 * k0.z;  acc3 += x3 * k0.w;
            acc0 += x1 * k1.x;  acc1 += x2 * k1.y;  acc2 += x3 * k1.z;  acc3 += x4 * k1.w;
            acc0 += x2 * k2.x;  acc1 += x3 * k2.y;  acc2 += x4 * k2.z;  acc3 += x5 * k2.w;
        }
        f32x4 o;
        o.x = acc0; o.y = acc1; o.z = acc2; o.w = acc3;
        __builtin_nontemporal_store(
            o, reinterpret_cast<f32x4*>(obase + (size_t)c * PHW + (size_t)h * PW + w0));
    }
}

extern "C" void kernel_launch(void* const* d_in, const int* in_sizes, int n_in,
                              void* d_out, int out_size, void* d_ws, size_t ws_size,
                              hipStream_t stream) {
    const float* input  = (const float*)d_in[0];
    const float* kernel = (const float*)d_in[1];
    float* out = (float*)d_out;

    PerPixelConv_kernel<<<PNBLK, PBLK, 0, stream>>>(input, kernel, out);
}